// Round 11
// baseline (1381.915 us; speedup 1.0000x reference)
//
#include <hip/hip_runtime.h>
#include <hip/hip_bf16.h>

#define NHID 256   // HEADS*H
#define HDIM 64
#define HEADS 4
#define LAYERS 5

// ---------------- CSR build ----------------
__global__ void count_deg(const int* __restrict__ dst, int* __restrict__ counts, int E) {
    int i = blockIdx.x * blockDim.x + threadIdx.x;
    if (i < E) atomicAdd(&counts[dst[i]], 1);
}

// hierarchical scan, phase 1: per-256-chunk exclusive scan + chunk total
__global__ __launch_bounds__(256) void scan_partial(const int* __restrict__ counts,
                                                    int* __restrict__ row_ptr,
                                                    int* __restrict__ partials, int n) {
    __shared__ int buf[256];
    int tid = threadIdx.x;
    int i = blockIdx.x * 256 + tid;
    int v = (i < n) ? counts[i] : 0;
    buf[tid] = v;
    __syncthreads();
    for (int o = 1; o < 256; o <<= 1) {
        int t = (tid >= o) ? buf[tid - o] : 0;
        __syncthreads();
        buf[tid] += t;
        __syncthreads();
    }
    if (i < n) row_ptr[i] = buf[tid] - v;          // exclusive within chunk
    if (tid == 255) partials[blockIdx.x] = buf[255];
}

// phase 2: single small block scans the (<=256) chunk totals; writes row_ptr[n]=grand total
__global__ __launch_bounds__(256) void scan_partials_scan(int* __restrict__ partials,
                                                          int* __restrict__ row_ptr,
                                                          int nblk, int n) {
    __shared__ int buf[256];
    int tid = threadIdx.x;
    int v = (tid < nblk) ? partials[tid] : 0;
    buf[tid] = v;
    __syncthreads();
    for (int o = 1; o < 256; o <<= 1) {
        int t = (tid >= o) ? buf[tid - o] : 0;
        __syncthreads();
        buf[tid] += t;
        __syncthreads();
    }
    if (tid < nblk) partials[tid] = buf[tid] - v;  // exclusive chunk offsets
    if (tid == 255) row_ptr[n] = buf[255];
}

// phase 3: add chunk offset (grid == nblk, blockDim == 256 to match chunking)
__global__ __launch_bounds__(256) void scan_add_offsets(int* __restrict__ row_ptr,
                                                        const int* __restrict__ partials, int n) {
    int i = blockIdx.x * 256 + threadIdx.x;
    if (i < n) row_ptr[i] += partials[blockIdx.x];
}

__global__ void copy_i32(const int* __restrict__ a, int* __restrict__ b, int n) {
    int i = blockIdx.x * blockDim.x + threadIdx.x;
    if (i < n) b[i] = a[i];
}

__global__ void scatter_edges(const int* __restrict__ src, const int* __restrict__ dst,
                              int* __restrict__ row_fill, int* __restrict__ col_src, int E) {
    int i = blockIdx.x * blockDim.x + threadIdx.x;
    if (i < E) {
        int p = atomicAdd(&row_fill[dst[i]], 1);
        col_src[p] = src[i];
    }
}

// ---------------- degree-sort (counting sort, 64 buckets) ----------------
__global__ void deg_hist(const int* __restrict__ row_ptr, int* __restrict__ hist, int n) {
    int i = blockIdx.x * blockDim.x + threadIdx.x;
    if (i < n) {
        int d = min(row_ptr[i + 1] - row_ptr[i], 63);
        atomicAdd(&hist[d], 1);
    }
}
__global__ __launch_bounds__(64) void hist_scan64(const int* __restrict__ hist,
                                                  int* __restrict__ offs) {
    __shared__ int buf[64];
    int t = threadIdx.x;
    buf[t] = hist[t];
    __syncthreads();
    if (t == 0) {
        int acc = 0;
        for (int i = 0; i < 64; ++i) { int v = buf[i]; buf[i] = acc; acc += v; }
    }
    __syncthreads();
    offs[t] = buf[t];
}
__global__ void deg_scatter(const int* __restrict__ row_ptr, int* __restrict__ offs,
                            int* __restrict__ perm, int n) {
    int i = blockIdx.x * blockDim.x + threadIdx.x;
    if (i < n) {
        int d = min(row_ptr[i + 1] - row_ptr[i], 63);
        int p = atomicAdd(&offs[d], 1);
        perm[p] = i;
    }
}

// ---------------- fused GEMM pair: xl/xr[n][256] = in[n][64] @ W + b ----------------
__global__ __launch_bounds__(256) void gemm2_64x256(const float* __restrict__ in,
                                                    const float* __restrict__ Wlg,
                                                    const float* __restrict__ blg,
                                                    const float* __restrict__ Wrg,
                                                    const float* __restrict__ brg,
                                                    float* __restrict__ xl,
                                                    float* __restrict__ xr, int n) {
    __shared__ float hs[16 * 64];
    int tid = threadIdx.x;
    int row0 = blockIdx.x * 16;
    const float4* in4 = (const float4*)(in + (size_t)row0 * 64);
    ((float4*)hs)[tid] = in4[tid];          // 16 rows x 64 cols
    __syncthreads();
    int col = tid;
    float accL[16], accR[16];
    float bL = blg[col], bR = brg[col];
#pragma unroll
    for (int r = 0; r < 16; ++r) { accL[r] = bL; accR[r] = bR; }
    for (int k = 0; k < 64; k += 4) {
        float wl0 = Wlg[(k + 0) * 256 + col], wr0 = Wrg[(k + 0) * 256 + col];
        float wl1 = Wlg[(k + 1) * 256 + col], wr1 = Wrg[(k + 1) * 256 + col];
        float wl2 = Wlg[(k + 2) * 256 + col], wr2 = Wrg[(k + 2) * 256 + col];
        float wl3 = Wlg[(k + 3) * 256 + col], wr3 = Wrg[(k + 3) * 256 + col];
#pragma unroll
        for (int r = 0; r < 16; ++r) {
            float4 hv = *(const float4*)&hs[r * 64 + k];   // ds_read_b128
            accL[r] += hv.x * wl0 + hv.y * wl1 + hv.z * wl2 + hv.w * wl3;
            accR[r] += hv.x * wr0 + hv.y * wr1 + hv.z * wr2 + hv.w * wr3;
        }
    }
#pragma unroll
    for (int r = 0; r < 16; ++r) {
        xl[(size_t)(row0 + r) * 256 + col] = accL[r];
        xr[(size_t)(row0 + r) * 256 + col] = accR[r];
    }
}

// ---------------- DPP helpers: 16-lane-group all-reduce sum ----------------
template <int CTRL>
__device__ __forceinline__ float dpp_mov_f32(float x) {
    return __int_as_float(__builtin_amdgcn_update_dpp(0, __float_as_int(x), CTRL, 0xf, 0xf, false));
}
// after this, every lane in each 16-lane group holds the group's sum
__device__ __forceinline__ float group16_reduce_add(float x) {
    x += dpp_mov_f32<0xB1>(x);    // quad_perm [1,0,3,2]  : xor 1
    x += dpp_mov_f32<0x4E>(x);    // quad_perm [2,3,0,1]  : xor 2
    x += dpp_mov_f32<0x124>(x);   // row_ror:4            : + next quad
    x += dpp_mov_f32<0x128>(x);   // row_ror:8            : + other half
    return x;
}

// ---------------- fused GATv2: 1 wave per node (degree-sorted), all 4 heads in-wave ----
// lane l: head = l>>4, covers row floats [4l, 4l+4)
__global__ __launch_bounds__(256) void gat_node(const float* __restrict__ xl,
                                                const float* __restrict__ xr,
                                                const int* __restrict__ row_ptr,
                                                const int* __restrict__ col_src,
                                                const int* __restrict__ perm,      // degree-sorted node order
                                                const float* __restrict__ att,     // [4][64] this layer
                                                const float* __restrict__ gbias,   // [64] this layer
                                                const float* __restrict__ h_res,   // residual or null
                                                float* __restrict__ h_out, int n) {
    int wid  = threadIdx.x >> 6;
    int lane = threadIdx.x & 63;
    int gid  = blockIdx.x * 4 + wid;
    if (gid >= n) return;
    int node = perm[gid];

    const float4* xl4 = (const float4*)xl;   // row = 64 float4
    float4 xrv = ((const float4*)(xr + (size_t)node * NHID))[lane];
    float4 av  = ((const float4*)att)[lane];
    // leaky_relu(z) = 0.6z + 0.4|z| exactly; pre-scale attention vector
    float4 av06 = make_float4(av.x * 0.6f, av.y * 0.6f, av.z * 0.6f, av.w * 0.6f);
    float4 av04 = make_float4(av.x * 0.4f, av.y * 0.4f, av.z * 0.4f, av.w * 0.4f);

    float  m = -INFINITY, s = 0.f;
    float4 acc = make_float4(0.f, 0.f, 0.f, 0.f);

    int e0 = row_ptr[node], e1 = row_ptr[node + 1];
    // edge idx in [e0, e1]; src(idx) = idx<e1 ? col_src[idx] : node (self loop)
    unsigned s0 = (e0 < e1) ? (unsigned)col_src[e0] : (unsigned)node;
    float4 xa = xl4[(size_t)s0 * 64 + lane];
    float4 xb;
    if (e0 + 1 <= e1) {
        unsigned s1 = (e0 + 1 < e1) ? (unsigned)col_src[e0 + 1] : (unsigned)node;
        xb = xl4[(size_t)s1 * 64 + lane];
    } else {
        xb = xa;
    }

    for (int idx = e0; idx <= e1; ++idx) {
        float4 cur = xa;
        xa = xb;
        int pf = idx + 2;
        if (pf <= e1) {
            unsigned sp = (pf < e1) ? (unsigned)col_src[pf] : (unsigned)node;
            xb = xl4[(size_t)sp * 64 + lane];
        }

        float z0 = cur.x + xrv.x;
        float z1 = cur.y + xrv.y;
        float z2 = cur.z + xrv.z;
        float z3 = cur.w + xrv.w;
        float pp;
        pp = fmaf(av06.x, z0, av04.x * fabsf(z0));
        pp = fmaf(av06.y, z1, fmaf(av04.y, fabsf(z1), pp));
        pp = fmaf(av06.z, z2, fmaf(av04.z, fabsf(z2), pp));
        pp = fmaf(av06.w, z3, fmaf(av04.w, fabsf(z3), pp));
        pp = group16_reduce_add(pp);            // per-head score, all lanes of group

        // deferred-max online softmax; branch wave-uniform via __any over heads
        if (__any(pp > m + 8.f)) {
            float mn = fmaxf(m, pp);            // exact online update
            float f  = __expf(m - mn);          // 0 on first edge (m=-inf)
            float w  = __expf(pp - mn);
            acc.x = acc.x * f + w * cur.x;
            acc.y = acc.y * f + w * cur.y;
            acc.z = acc.z * f + w * cur.z;
            acc.w = acc.w * f + w * cur.w;
            s = s * f + w;
            m = mn;
        } else {
            float w = __expf(pp - m);           // bounded by e^8
            acc.x += w * cur.x;
            acc.y += w * cur.y;
            acc.z += w * cur.z;
            acc.w += w * cur.w;
            s += w;
        }
    }

    // per-head weighted mean
    float inv = 1.0f / s;
    float4 v = make_float4(acc.x * inv, acc.y * inv, acc.z * inv, acc.w * inv);
    // cross-head sum: lanes l, l^16, l^32, l^48 hold same channels of heads 0..3
    v.x += __shfl_xor(v.x, 16, 64); v.y += __shfl_xor(v.y, 16, 64);
    v.z += __shfl_xor(v.z, 16, 64); v.w += __shfl_xor(v.w, 16, 64);
    v.x += __shfl_xor(v.x, 32, 64); v.y += __shfl_xor(v.y, 32, 64);
    v.z += __shfl_xor(v.z, 32, 64); v.w += __shfl_xor(v.w, 32, 64);

    if (lane < 16) {
        float4 g = ((const float4*)gbias)[lane];
        float4 o;
        o.x = v.x * 0.25f + g.x;
        o.y = v.y * 0.25f + g.y;
        o.z = v.z * 0.25f + g.z;
        o.w = v.w * 0.25f + g.w;
        o.x = (o.x > 0.f) ? o.x : expm1f(o.x);
        o.y = (o.y > 0.f) ? o.y : expm1f(o.y);
        o.z = (o.z > 0.f) ? o.z : expm1f(o.z);
        o.w = (o.w > 0.f) ? o.w : expm1f(o.w);
        if (h_res) {
            float4 r = ((const float4*)(h_res + (size_t)node * 64))[lane];
            o.x += r.x; o.y += r.y; o.z += r.z; o.w += r.w;
        }
        ((float4*)(h_out + (size_t)node * 64))[lane] = o;
    }
}

// ---------------- column mean of h over all nodes ----------------
__global__ __launch_bounds__(256) void col_sum(const float* __restrict__ h,
                                               float* __restrict__ gsum, int n) {
    int col = threadIdx.x & 63;
    int sub = threadIdx.x >> 6;   // 0..3
    float s = 0.f;
    for (int r = blockIdx.x * 4 + sub; r < n; r += gridDim.x * 4)
        s += h[(size_t)r * 64 + col];
    __shared__ float tmp[4][64];
    tmp[sub][col] = s;
    __syncthreads();
    if (threadIdx.x < 64) {
        int t = threadIdx.x;
        atomicAdd(&gsum[t], tmp[0][t] + tmp[1][t] + tmp[2][t] + tmp[3][t]);
    }
}

// ---------------- output heads, parallel: blocks 0-8 move, 9 price, 10 value ----------
__global__ __launch_bounds__(128) void heads_kernel(const float* __restrict__ h,
                                                    const float* __restrict__ gsum,
                                                    const int* __restrict__ cur_pos,
                                                    const int* __restrict__ valid,
                                                    const int* __restrict__ owned,
                                                    const float* __restrict__ Wm1, const float* __restrict__ bm1,
                                                    const float* __restrict__ Wm2, const float* __restrict__ bm2,
                                                    const float* __restrict__ Wp,  const float* __restrict__ bp,
                                                    const float* __restrict__ Wv1, const float* __restrict__ bv1,
                                                    const float* __restrict__ Wv2, const float* __restrict__ bv2,
                                                    float* __restrict__ out, int n) {
    int blk = blockIdx.x;
    int tid = threadIdx.x;
    int pos = cur_pos[0];

    if (blk < 9) {
        // move logit for candidate blk: hid[tid] over 128 threads, then reduce
        int cand = (blk == 0) ? pos : valid[blk - 1];
        const float* hcur  = h + (size_t)pos  * 64;
        const float* hcand = h + (size_t)cand * 64;
        float a = bm1[tid];
#pragma unroll
        for (int k = 0; k < 64; ++k) a += hcur[k]  * Wm1[k * 128 + tid];
#pragma unroll
        for (int k = 0; k < 64; ++k) a += hcand[k] * Wm1[(64 + k) * 128 + tid];
        a = fmaxf(a, 0.f) * Wm2[tid];
#pragma unroll
        for (int o = 1; o < 64; o <<= 1) a += __shfl_xor(a, o, 64);
        __shared__ float red[2];
        if ((tid & 63) == 0) red[tid >> 6] = a;
        __syncthreads();
        if (tid == 0) out[blk] = red[0] + red[1] + bm2[0];
    } else if (blk == 9) {
        // price logits: 10 nodes x 3
        if (tid < 30) {
            int i = tid / 3, cc = tid % 3;
            int node = owned[i];
            const float* hn = h + (size_t)node * 64;
            float a = bp[cc];
#pragma unroll
            for (int k = 0; k < 64; ++k) a += hn[k] * Wp[k * 3 + cc];
            out[9 + tid] = a;
        }
    } else {
        // value head: g = [gsum/n, h[pos]]
        float invn = 1.0f / (float)n;
        const float* hcur = h + (size_t)pos * 64;
        float a = 0.f;
        if (tid < 64) {
            a = bv1[tid];
#pragma unroll
            for (int k = 0; k < 64; ++k) a += (gsum[k] * invn) * Wv1[k * 64 + tid];
#pragma unroll
            for (int k = 0; k < 64; ++k) a += hcur[k] * Wv1[(64 + k) * 64 + tid];
            a = fmaxf(a, 0.f) * Wv2[tid];
#pragma unroll
            for (int o = 1; o < 64; o <<= 1) a += __shfl_xor(a, o, 64);
            if (tid == 0) out[39] = a + bv2[0];
        }
    }
}

extern "C" void kernel_launch(void* const* d_in, const int* in_sizes, int n_in,
                              void* d_out, int out_size, void* d_ws, size_t ws_size,
                              hipStream_t stream) {
    const float* nf    = (const float*)d_in[0];
    const int*   ei    = (const int*)d_in[1];
    const int*   cpos  = (const int*)d_in[2];
    const int*   valid = (const int*)d_in[3];
    const int*   owned = (const int*)d_in[4];
    const float* Wl    = (const float*)d_in[5];
    const float* bl    = (const float*)d_in[6];
    const float* Wr    = (const float*)d_in[7];
    const float* br    = (const float*)d_in[8];
    const float* att   = (const float*)d_in[9];
    const float* gbias = (const float*)d_in[10];
    const float* Wm1 = (const float*)d_in[11];
    const float* bm1 = (const float*)d_in[12];
    const float* Wm2 = (const float*)d_in[13];
    const float* bm2 = (const float*)d_in[14];
    const float* Wp  = (const float*)d_in[15];
    const float* bp  = (const float*)d_in[16];
    const float* Wv1 = (const float*)d_in[17];
    const float* bv1 = (const float*)d_in[18];
    const float* Wv2 = (const float*)d_in[19];
    const float* bv2 = (const float*)d_in[20];
    float* out = (float*)d_out;

    int n = in_sizes[0] / 64;      // 50000
    int E = in_sizes[1] / 2;       // 800000
    const int* srcp = ei;
    const int* dstp = ei + E;

    // workspace carve
    char* w = (char*)d_ws;
    auto alloc = [&](size_t bytes) -> char* {
        char* p = w;
        w += (bytes + 255) & ~(size_t)255;
        return p;
    };
    float* xl       = (float*)alloc((size_t)n * NHID * 4);
    float* xr       = (float*)alloc((size_t)n * NHID * 4);
    float* hA       = (float*)alloc((size_t)n * 64 * 4);
    float* hB       = (float*)alloc((size_t)n * 64 * 4);
    float* gsum     = (float*)alloc(64 * 4);
    int*   row_ptr  = (int*)alloc((size_t)(n + 1) * 4);
    int*   row_fill = (int*)alloc((size_t)n * 4);
    int*   col_src  = (int*)alloc((size_t)E * 4);
    int*   partials = (int*)alloc(256 * 4);
    int*   hist     = (int*)alloc(64 * 4);
    int*   offs     = (int*)alloc(64 * 4);
    int*   perm     = (int*)alloc((size_t)n * 4);

    int nblk = (n + 255) / 256;    // 196

    // ---- CSR by dst ----
    hipMemsetAsync(row_fill, 0, (size_t)n * 4, stream);
    count_deg<<<(E + 255) / 256, 256, 0, stream>>>(dstp, row_fill, E);
    scan_partial<<<nblk, 256, 0, stream>>>(row_fill, row_ptr, partials, n);
    scan_partials_scan<<<1, 256, 0, stream>>>(partials, row_ptr, nblk, n);
    scan_add_offsets<<<nblk, 256, 0, stream>>>(row_ptr, partials, n);
    copy_i32<<<(n + 255) / 256, 256, 0, stream>>>(row_ptr, row_fill, n);
    scatter_edges<<<(E + 255) / 256, 256, 0, stream>>>(srcp, dstp, row_fill, col_src, E);

    // ---- degree-sorted node permutation (load balance for gat_node) ----
    hipMemsetAsync(hist, 0, 64 * 4, stream);
    deg_hist<<<nblk, 256, 0, stream>>>(row_ptr, hist, n);
    hist_scan64<<<1, 64, 0, stream>>>(hist, offs);
    deg_scatter<<<nblk, 256, 0, stream>>>(row_ptr, offs, perm, n);

    // ---- 5 GATv2 layers ----
    const float* hin = nf;
    float* hnext = hB;
    for (int i = 0; i < LAYERS; ++i) {
        const float* Wli = Wl + (size_t)i * 64 * 256;
        const float* Wri = Wr + (size_t)i * 64 * 256;
        gemm2_64x256<<<(n + 15) / 16, 256, 0, stream>>>(hin, Wli, bl + i * 256,
                                                        Wri, br + i * 256, xl, xr, n);
        const float* res = (i == 0) ? nullptr : hin;
        float* outp = (i == 0) ? hA : hnext;
        gat_node<<<(n + 3) / 4, 256, 0, stream>>>(xl, xr, row_ptr, col_src, perm,
                                                  att + i * HEADS * 64, gbias + i * 64,
                                                  res, outp, n);
        if (i == 0) {
            hin = hA; hnext = hB;
        } else {
            const float* t = hin;
            hin = outp;
            hnext = (float*)t;
        }
    }

    // ---- heads ----
    hipMemsetAsync(gsum, 0, 64 * 4, stream);
    col_sum<<<256, 256, 0, stream>>>(hin, gsum, n);
    heads_kernel<<<11, 128, 0, stream>>>(hin, gsum, cpos, valid, owned,
                                         Wm1, bm1, Wm2, bm2, Wp, bp,
                                         Wv1, bv1, Wv2, bv2, out, n);
}

// Round 13
// 1123.274 us; speedup vs baseline: 1.2303x; 1.2303x over previous
//
#include <hip/hip_runtime.h>
#include <hip/hip_bf16.h>

#define NHID 256   // HEADS*H
#define HDIM 64
#define HEADS 4
#define LAYERS 5

// ---------------- CSR build ----------------
__global__ void count_deg(const int* __restrict__ dst, int* __restrict__ counts, int E) {
    int i = blockIdx.x * blockDim.x + threadIdx.x;
    if (i < E) atomicAdd(&counts[dst[i]], 1);
}

// hierarchical scan, phase 1: per-256-chunk exclusive scan + chunk total
__global__ __launch_bounds__(256) void scan_partial(const int* __restrict__ counts,
                                                    int* __restrict__ out,
                                                    int* __restrict__ partials, int n) {
    __shared__ int buf[256];
    int tid = threadIdx.x;
    int i = blockIdx.x * 256 + tid;
    int v = (i < n) ? counts[i] : 0;
    buf[tid] = v;
    __syncthreads();
    for (int o = 1; o < 256; o <<= 1) {
        int t = (tid >= o) ? buf[tid - o] : 0;
        __syncthreads();
        buf[tid] += t;
        __syncthreads();
    }
    if (i < n) out[i] = buf[tid] - v;              // exclusive within chunk
    if (tid == 255) partials[blockIdx.x] = buf[255];
}

// phase 2: single small block scans the (<=256) chunk totals; writes out[n]=grand total
__global__ __launch_bounds__(256) void scan_partials_scan(int* __restrict__ partials,
                                                          int* __restrict__ out,
                                                          int nblk, int n) {
    __shared__ int buf[256];
    int tid = threadIdx.x;
    int v = (tid < nblk) ? partials[tid] : 0;
    buf[tid] = v;
    __syncthreads();
    for (int o = 1; o < 256; o <<= 1) {
        int t = (tid >= o) ? buf[tid - o] : 0;
        __syncthreads();
        buf[tid] += t;
        __syncthreads();
    }
    if (tid < nblk) partials[tid] = buf[tid] - v;  // exclusive chunk offsets
    if (tid == 255) out[n] = buf[255];
}

// phase 3: add chunk offset (grid == nblk, blockDim == 256 to match chunking)
__global__ __launch_bounds__(256) void scan_add_offsets(int* __restrict__ out,
                                                        const int* __restrict__ partials, int n) {
    int i = blockIdx.x * 256 + threadIdx.x;
    if (i < n) out[i] += partials[blockIdx.x];
}

__global__ void copy_i32(const int* __restrict__ a, int* __restrict__ b, int n) {
    int i = blockIdx.x * blockDim.x + threadIdx.x;
    if (i < n) b[i] = a[i];
}

__global__ void scatter_edges(const int* __restrict__ src, const int* __restrict__ dst,
                              int* __restrict__ row_fill, int* __restrict__ col_src, int E) {
    int i = blockIdx.x * blockDim.x + threadIdx.x;
    if (i < E) {
        int p = atomicAdd(&row_fill[dst[i]], 1);
        col_src[p] = src[i];
    }
}

// ---------------- contention-free degree counting sort ----------------
// Phase A: per-block LDS histogram + local rank; hist2 laid out degree-major [64][nblk]
__global__ __launch_bounds__(256) void sortA(const int* __restrict__ row_ptr,
                                             int* __restrict__ hist2,
                                             int* __restrict__ rankbuf, int n, int nblk) {
    __shared__ int lh[64];
    int tid = threadIdx.x;
    if (tid < 64) lh[tid] = 0;
    __syncthreads();
    int i = blockIdx.x * 256 + tid;
    if (i < n) {
        int d = min(row_ptr[i + 1] - row_ptr[i], 63);
        rankbuf[i] = atomicAdd(&lh[d], 1);      // LDS atomic: fast
    }
    __syncthreads();
    if (tid < 64) hist2[tid * nblk + blockIdx.x] = lh[tid];
}
// Phase C: scatter node i to perm[scannedhist[d][blk] + rank]
__global__ __launch_bounds__(256) void sortC(const int* __restrict__ row_ptr,
                                             const int* __restrict__ hist2s,
                                             const int* __restrict__ rankbuf,
                                             int* __restrict__ perm, int n, int nblk) {
    int i = blockIdx.x * 256 + threadIdx.x;
    if (i < n) {
        int d = min(row_ptr[i + 1] - row_ptr[i], 63);
        perm[hist2s[d * nblk + blockIdx.x] + rankbuf[i]] = i;
    }
}

// ---------------- fused GEMM pair: xl/xr[n][256] = in[n][64] @ W + b ----------------
__global__ __launch_bounds__(256) void gemm2_64x256(const float* __restrict__ in,
                                                    const float* __restrict__ Wlg,
                                                    const float* __restrict__ blg,
                                                    const float* __restrict__ Wrg,
                                                    const float* __restrict__ brg,
                                                    float* __restrict__ xl,
                                                    float* __restrict__ xr, int n) {
    __shared__ float hs[16 * 64];
    int tid = threadIdx.x;
    int row0 = blockIdx.x * 16;
    const float4* in4 = (const float4*)(in + (size_t)row0 * 64);
    ((float4*)hs)[tid] = in4[tid];          // 16 rows x 64 cols
    __syncthreads();
    int col = tid;
    float accL[16], accR[16];
    float bL = blg[col], bR = brg[col];
#pragma unroll
    for (int r = 0; r < 16; ++r) { accL[r] = bL; accR[r] = bR; }
    for (int k = 0; k < 64; k += 4) {
        float wl0 = Wlg[(k + 0) * 256 + col], wr0 = Wrg[(k + 0) * 256 + col];
        float wl1 = Wlg[(k + 1) * 256 + col], wr1 = Wrg[(k + 1) * 256 + col];
        float wl2 = Wlg[(k + 2) * 256 + col], wr2 = Wrg[(k + 2) * 256 + col];
        float wl3 = Wlg[(k + 3) * 256 + col], wr3 = Wrg[(k + 3) * 256 + col];
#pragma unroll
        for (int r = 0; r < 16; ++r) {
            float4 hv = *(const float4*)&hs[r * 64 + k];   // ds_read_b128
            accL[r] += hv.x * wl0 + hv.y * wl1 + hv.z * wl2 + hv.w * wl3;
            accR[r] += hv.x * wr0 + hv.y * wr1 + hv.z * wr2 + hv.w * wr3;
        }
    }
#pragma unroll
    for (int r = 0; r < 16; ++r) {
        xl[(size_t)(row0 + r) * 256 + col] = accL[r];
        xr[(size_t)(row0 + r) * 256 + col] = accR[r];
    }
}

// ---------------- DPP helpers: 16-lane-group all-reduce sum ----------------
template <int CTRL>
__device__ __forceinline__ float dpp_mov_f32(float x) {
    return __int_as_float(__builtin_amdgcn_update_dpp(0, __float_as_int(x), CTRL, 0xf, 0xf, false));
}
// after this, every lane in each 16-lane group holds the group's sum
__device__ __forceinline__ float group16_reduce_add(float x) {
    x += dpp_mov_f32<0xB1>(x);    // quad_perm [1,0,3,2]  : xor 1
    x += dpp_mov_f32<0x4E>(x);    // quad_perm [2,3,0,1]  : xor 2
    x += dpp_mov_f32<0x124>(x);   // row_ror:4            : + next quad
    x += dpp_mov_f32<0x128>(x);   // row_ror:8            : + other half
    return x;
}

// ---------------- fused GATv2: 1 wave per node (degree-sorted), all 4 heads in-wave ----
// lane l: head = l>>4, covers row floats [4l, 4l+4)
__global__ __launch_bounds__(256) void gat_node(const float* __restrict__ xl,
                                                const float* __restrict__ xr,
                                                const int* __restrict__ row_ptr,
                                                const int* __restrict__ col_src,
                                                const int* __restrict__ perm,      // degree-sorted node order
                                                const float* __restrict__ att,     // [4][64] this layer
                                                const float* __restrict__ gbias,   // [64] this layer
                                                const float* __restrict__ h_res,   // residual or null
                                                float* __restrict__ h_out, int n) {
    int wid  = threadIdx.x >> 6;
    int lane = threadIdx.x & 63;
    int gid  = blockIdx.x * 4 + wid;
    if (gid >= n) return;
    int node = perm[gid];

    const float4* xl4 = (const float4*)xl;   // row = 64 float4
    float4 xrv = ((const float4*)(xr + (size_t)node * NHID))[lane];
    float4 av  = ((const float4*)att)[lane];
    // leaky_relu(z) = 0.6z + 0.4|z| exactly; pre-scale attention vector
    float4 av06 = make_float4(av.x * 0.6f, av.y * 0.6f, av.z * 0.6f, av.w * 0.6f);
    float4 av04 = make_float4(av.x * 0.4f, av.y * 0.4f, av.z * 0.4f, av.w * 0.4f);

    float  m = -INFINITY, s = 0.f;
    float4 acc = make_float4(0.f, 0.f, 0.f, 0.f);

    int e0 = row_ptr[node], e1 = row_ptr[node + 1];
    // edge idx in [e0, e1]; src(idx) = idx<e1 ? col_src[idx] : node (self loop)
    unsigned s0 = (e0 < e1) ? (unsigned)col_src[e0] : (unsigned)node;
    float4 xa = xl4[(size_t)s0 * 64 + lane];
    float4 xb;
    if (e0 + 1 <= e1) {
        unsigned s1 = (e0 + 1 < e1) ? (unsigned)col_src[e0 + 1] : (unsigned)node;
        xb = xl4[(size_t)s1 * 64 + lane];
    } else {
        xb = xa;
    }

    for (int idx = e0; idx <= e1; ++idx) {
        float4 cur = xa;
        xa = xb;
        int pf = idx + 2;
        if (pf <= e1) {
            unsigned sp = (pf < e1) ? (unsigned)col_src[pf] : (unsigned)node;
            xb = xl4[(size_t)sp * 64 + lane];
        }

        float z0 = cur.x + xrv.x;
        float z1 = cur.y + xrv.y;
        float z2 = cur.z + xrv.z;
        float z3 = cur.w + xrv.w;
        float pp;
        pp = fmaf(av06.x, z0, av04.x * fabsf(z0));
        pp = fmaf(av06.y, z1, fmaf(av04.y, fabsf(z1), pp));
        pp = fmaf(av06.z, z2, fmaf(av04.z, fabsf(z2), pp));
        pp = fmaf(av06.w, z3, fmaf(av04.w, fabsf(z3), pp));
        pp = group16_reduce_add(pp);            // per-head score, all lanes of group

        // deferred-max online softmax; branch wave-uniform via __any over heads
        if (__any(pp > m + 8.f)) {
            float mn = fmaxf(m, pp);            // exact online update
            float f  = __expf(m - mn);          // 0 on first edge (m=-inf)
            float w  = __expf(pp - mn);
            acc.x = acc.x * f + w * cur.x;
            acc.y = acc.y * f + w * cur.y;
            acc.z = acc.z * f + w * cur.z;
            acc.w = acc.w * f + w * cur.w;
            s = s * f + w;
            m = mn;
        } else {
            float w = __expf(pp - m);           // bounded by e^8
            acc.x += w * cur.x;
            acc.y += w * cur.y;
            acc.z += w * cur.z;
            acc.w += w * cur.w;
            s += w;
        }
    }

    // per-head weighted mean
    float inv = 1.0f / s;
    float4 v = make_float4(acc.x * inv, acc.y * inv, acc.z * inv, acc.w * inv);
    // cross-head sum: lanes l, l^16, l^32, l^48 hold same channels of heads 0..3
    v.x += __shfl_xor(v.x, 16, 64); v.y += __shfl_xor(v.y, 16, 64);
    v.z += __shfl_xor(v.z, 16, 64); v.w += __shfl_xor(v.w, 16, 64);
    v.x += __shfl_xor(v.x, 32, 64); v.y += __shfl_xor(v.y, 32, 64);
    v.z += __shfl_xor(v.z, 32, 64); v.w += __shfl_xor(v.w, 32, 64);

    if (lane < 16) {
        float4 g = ((const float4*)gbias)[lane];
        float4 o;
        o.x = v.x * 0.25f + g.x;
        o.y = v.y * 0.25f + g.y;
        o.z = v.z * 0.25f + g.z;
        o.w = v.w * 0.25f + g.w;
        o.x = (o.x > 0.f) ? o.x : expm1f(o.x);
        o.y = (o.y > 0.f) ? o.y : expm1f(o.y);
        o.z = (o.z > 0.f) ? o.z : expm1f(o.z);
        o.w = (o.w > 0.f) ? o.w : expm1f(o.w);
        if (h_res) {
            float4 r = ((const float4*)(h_res + (size_t)node * 64))[lane];
            o.x += r.x; o.y += r.y; o.z += r.z; o.w += r.w;
        }
        ((float4*)(h_out + (size_t)node * 64))[lane] = o;
    }
}

// ---------------- column mean of h over all nodes ----------------
__global__ __launch_bounds__(256) void col_sum(const float* __restrict__ h,
                                               float* __restrict__ gsum, int n) {
    int col = threadIdx.x & 63;
    int sub = threadIdx.x >> 6;   // 0..3
    float s = 0.f;
    for (int r = blockIdx.x * 4 + sub; r < n; r += gridDim.x * 4)
        s += h[(size_t)r * 64 + col];
    __shared__ float tmp[4][64];
    tmp[sub][col] = s;
    __syncthreads();
    if (threadIdx.x < 64) {
        int t = threadIdx.x;
        atomicAdd(&gsum[t], tmp[0][t] + tmp[1][t] + tmp[2][t] + tmp[3][t]);
    }
}

// ---------------- output heads, parallel: blocks 0-8 move, 9 price, 10 value ----------
__global__ __launch_bounds__(128) void heads_kernel(const float* __restrict__ h,
                                                    const float* __restrict__ gsum,
                                                    const int* __restrict__ cur_pos,
                                                    const int* __restrict__ valid,
                                                    const int* __restrict__ owned,
                                                    const float* __restrict__ Wm1, const float* __restrict__ bm1,
                                                    const float* __restrict__ Wm2, const float* __restrict__ bm2,
                                                    const float* __restrict__ Wp,  const float* __restrict__ bp,
                                                    const float* __restrict__ Wv1, const float* __restrict__ bv1,
                                                    const float* __restrict__ Wv2, const float* __restrict__ bv2,
                                                    float* __restrict__ out, int n) {
    int blk = blockIdx.x;
    int tid = threadIdx.x;
    int pos = cur_pos[0];

    if (blk < 9) {
        // move logit for candidate blk: hid[tid] over 128 threads, then reduce
        int cand = (blk == 0) ? pos : valid[blk - 1];
        const float* hcur  = h + (size_t)pos  * 64;
        const float* hcand = h + (size_t)cand * 64;
        float a = bm1[tid];
#pragma unroll
        for (int k = 0; k < 64; ++k) a += hcur[k]  * Wm1[k * 128 + tid];
#pragma unroll
        for (int k = 0; k < 64; ++k) a += hcand[k] * Wm1[(64 + k) * 128 + tid];
        a = fmaxf(a, 0.f) * Wm2[tid];
#pragma unroll
        for (int o = 1; o < 64; o <<= 1) a += __shfl_xor(a, o, 64);
        __shared__ float red[2];
        if ((tid & 63) == 0) red[tid >> 6] = a;
        __syncthreads();
        if (tid == 0) out[blk] = red[0] + red[1] + bm2[0];
    } else if (blk == 9) {
        // price logits: 10 nodes x 3
        if (tid < 30) {
            int i = tid / 3, cc = tid % 3;
            int node = owned[i];
            const float* hn = h + (size_t)node * 64;
            float a = bp[cc];
#pragma unroll
            for (int k = 0; k < 64; ++k) a += hn[k] * Wp[k * 3 + cc];
            out[9 + tid] = a;
        }
    } else {
        // value head: g = [gsum/n, h[pos]]
        float invn = 1.0f / (float)n;
        const float* hcur = h + (size_t)pos * 64;
        float a = 0.f;
        if (tid < 64) {
            a = bv1[tid];
#pragma unroll
            for (int k = 0; k < 64; ++k) a += (gsum[k] * invn) * Wv1[k * 64 + tid];
#pragma unroll
            for (int k = 0; k < 64; ++k) a += hcur[k] * Wv1[(64 + k) * 64 + tid];
            a = fmaxf(a, 0.f) * Wv2[tid];
#pragma unroll
            for (int o = 1; o < 64; o <<= 1) a += __shfl_xor(a, o, 64);
            if (tid == 0) out[39] = a + bv2[0];
        }
    }
}

extern "C" void kernel_launch(void* const* d_in, const int* in_sizes, int n_in,
                              void* d_out, int out_size, void* d_ws, size_t ws_size,
                              hipStream_t stream) {
    const float* nf    = (const float*)d_in[0];
    const int*   ei    = (const int*)d_in[1];
    const int*   cpos  = (const int*)d_in[2];
    const int*   valid = (const int*)d_in[3];
    const int*   owned = (const int*)d_in[4];
    const float* Wl    = (const float*)d_in[5];
    const float* bl    = (const float*)d_in[6];
    const float* Wr    = (const float*)d_in[7];
    const float* br    = (const float*)d_in[8];
    const float* att   = (const float*)d_in[9];
    const float* gbias = (const float*)d_in[10];
    const float* Wm1 = (const float*)d_in[11];
    const float* bm1 = (const float*)d_in[12];
    const float* Wm2 = (const float*)d_in[13];
    const float* bm2 = (const float*)d_in[14];
    const float* Wp  = (const float*)d_in[15];
    const float* bp  = (const float*)d_in[16];
    const float* Wv1 = (const float*)d_in[17];
    const float* bv1 = (const float*)d_in[18];
    const float* Wv2 = (const float*)d_in[19];
    const float* bv2 = (const float*)d_in[20];
    float* out = (float*)d_out;

    int n = in_sizes[0] / 64;      // 50000
    int E = in_sizes[1] / 2;       // 800000
    const int* srcp = ei;
    const int* dstp = ei + E;

    // workspace carve
    char* w = (char*)d_ws;
    auto alloc = [&](size_t bytes) -> char* {
        char* p = w;
        w += (bytes + 255) & ~(size_t)255;
        return p;
    };
    float* xl       = (float*)alloc((size_t)n * NHID * 4);
    float* xr       = (float*)alloc((size_t)n * NHID * 4);
    float* hA       = (float*)alloc((size_t)n * 64 * 4);
    float* hB       = (float*)alloc((size_t)n * 64 * 4);
    float* gsum     = (float*)alloc(64 * 4);
    int*   row_ptr  = (int*)alloc((size_t)(n + 1) * 4);
    int*   row_fill = (int*)alloc((size_t)n * 4);
    int*   col_src  = (int*)alloc((size_t)E * 4);
    int*   partials = (int*)alloc(256 * 4);

    int nblk = (n + 255) / 256;    // 196
    int nscan = 64 * nblk;         // 12544
    int nblk2 = (nscan + 255) / 256;

    int*   hist2    = (int*)alloc((size_t)nscan * 4);
    int*   hist2s   = (int*)alloc((size_t)(nscan + 1) * 4);
    int*   rankbuf  = (int*)alloc((size_t)n * 4);
    int*   perm     = (int*)alloc((size_t)n * 4);

    // ---- CSR by dst ----
    hipMemsetAsync(row_fill, 0, (size_t)n * 4, stream);
    count_deg<<<(E + 255) / 256, 256, 0, stream>>>(dstp, row_fill, E);
    scan_partial<<<nblk, 256, 0, stream>>>(row_fill, row_ptr, partials, n);
    scan_partials_scan<<<1, 256, 0, stream>>>(partials, row_ptr, nblk, n);
    scan_add_offsets<<<nblk, 256, 0, stream>>>(row_ptr, partials, n);
    copy_i32<<<(n + 255) / 256, 256, 0, stream>>>(row_ptr, row_fill, n);
    scatter_edges<<<(E + 255) / 256, 256, 0, stream>>>(srcp, dstp, row_fill, col_src, E);

    // ---- contention-free degree counting sort ----
    sortA<<<nblk, 256, 0, stream>>>(row_ptr, hist2, rankbuf, n, nblk);
    scan_partial<<<nblk2, 256, 0, stream>>>(hist2, hist2s, partials, nscan);
    scan_partials_scan<<<1, 256, 0, stream>>>(partials, hist2s, nblk2, nscan);
    scan_add_offsets<<<nblk2, 256, 0, stream>>>(hist2s, partials, nscan);
    sortC<<<nblk, 256, 0, stream>>>(row_ptr, hist2s, rankbuf, perm, n, nblk);

    // ---- 5 GATv2 layers ----
    const float* hin = nf;
    float* hnext = hB;
    for (int i = 0; i < LAYERS; ++i) {
        const float* Wli = Wl + (size_t)i * 64 * 256;
        const float* Wri = Wr + (size_t)i * 64 * 256;
        gemm2_64x256<<<(n + 15) / 16, 256, 0, stream>>>(hin, Wli, bl + i * 256,
                                                        Wri, br + i * 256, xl, xr, n);
        const float* res = (i == 0) ? nullptr : hin;
        float* outp = (i == 0) ? hA : hnext;
        gat_node<<<(n + 3) / 4, 256, 0, stream>>>(xl, xr, row_ptr, col_src, perm,
                                                  att + i * HEADS * 64, gbias + i * 64,
                                                  res, outp, n);
        if (i == 0) {
            hin = hA; hnext = hB;
        } else {
            const float* t = hin;
            hin = outp;
            hnext = (float*)t;
        }
    }

    // ---- heads ----
    hipMemsetAsync(gsum, 0, 64 * 4, stream);
    col_sum<<<256, 256, 0, stream>>>(hin, gsum, n);
    heads_kernel<<<11, 128, 0, stream>>>(hin, gsum, cpos, valid, owned,
                                         Wm1, bm1, Wm2, bm2, Wp, bp,
                                         Wv1, bv1, Wv2, bv2, out, n);
}

// Round 14
// 1078.114 us; speedup vs baseline: 1.2818x; 1.0419x over previous
//
#include <hip/hip_runtime.h>
#include <hip/hip_bf16.h>

#define NHID 256   // HEADS*H
#define HDIM 64
#define HEADS 4
#define LAYERS 5

// ---------------- CSR build ----------------
__global__ void count_deg(const int* __restrict__ dst, int* __restrict__ counts, int E) {
    int i = blockIdx.x * blockDim.x + threadIdx.x;
    if (i < E) atomicAdd(&counts[dst[i]], 1);
}

// hierarchical scan, phase 1: per-256-chunk exclusive scan + chunk total
__global__ __launch_bounds__(256) void scan_partial(const int* __restrict__ counts,
                                                    int* __restrict__ out,
                                                    int* __restrict__ partials, int n) {
    __shared__ int buf[256];
    int tid = threadIdx.x;
    int i = blockIdx.x * 256 + tid;
    int v = (i < n) ? counts[i] : 0;
    buf[tid] = v;
    __syncthreads();
    for (int o = 1; o < 256; o <<= 1) {
        int t = (tid >= o) ? buf[tid - o] : 0;
        __syncthreads();
        buf[tid] += t;
        __syncthreads();
    }
    if (i < n) out[i] = buf[tid] - v;              // exclusive within chunk
    if (tid == 255) partials[blockIdx.x] = buf[255];
}

// phase 2: single small block scans the (<=256) chunk totals; writes out[n]=grand total
__global__ __launch_bounds__(256) void scan_partials_scan(int* __restrict__ partials,
                                                          int* __restrict__ out,
                                                          int nblk, int n) {
    __shared__ int buf[256];
    int tid = threadIdx.x;
    int v = (tid < nblk) ? partials[tid] : 0;
    buf[tid] = v;
    __syncthreads();
    for (int o = 1; o < 256; o <<= 1) {
        int t = (tid >= o) ? buf[tid - o] : 0;
        __syncthreads();
        buf[tid] += t;
        __syncthreads();
    }
    if (tid < nblk) partials[tid] = buf[tid] - v;  // exclusive chunk offsets
    if (tid == 255) out[n] = buf[255];
}

// phase 3: add chunk offset (grid == nblk, blockDim == 256 to match chunking)
__global__ __launch_bounds__(256) void scan_add_offsets(int* __restrict__ out,
                                                        const int* __restrict__ partials, int n) {
    int i = blockIdx.x * 256 + threadIdx.x;
    if (i < n) out[i] += partials[blockIdx.x];
}

__global__ void copy_i32(const int* __restrict__ a, int* __restrict__ b, int n) {
    int i = blockIdx.x * blockDim.x + threadIdx.x;
    if (i < n) b[i] = a[i];
}

__global__ void scatter_edges(const int* __restrict__ src, const int* __restrict__ dst,
                              int* __restrict__ row_fill, int* __restrict__ col_src, int E) {
    int i = blockIdx.x * blockDim.x + threadIdx.x;
    if (i < E) {
        int p = atomicAdd(&row_fill[dst[i]], 1);
        col_src[p] = src[i];
    }
}

// ---------------- fused GEMM pair, LDS-free: h-tile read via SCALAR loads ----------
// thread = output col (256); block = 16 rows. in[(row0+r)*64+k] is block-uniform ->
// compiler emits s_load_dwordx4 (scalar pipe, parallel to VALU). Inner loop is FMA-bound.
__global__ __launch_bounds__(256) void gemm2_64x256(const float* __restrict__ in,
                                                    const float* __restrict__ Wlg,
                                                    const float* __restrict__ blg,
                                                    const float* __restrict__ Wrg,
                                                    const float* __restrict__ brg,
                                                    float* __restrict__ xl,
                                                    float* __restrict__ xr, int n) {
    int col = threadIdx.x;
    int row0 = blockIdx.x * 16;
    float accL[16], accR[16];
    float bL = blg[col], bR = brg[col];
#pragma unroll
    for (int r = 0; r < 16; ++r) { accL[r] = bL; accR[r] = bR; }
    for (int k = 0; k < 64; k += 4) {
        float wl0 = Wlg[(k + 0) * 256 + col], wr0 = Wrg[(k + 0) * 256 + col];
        float wl1 = Wlg[(k + 1) * 256 + col], wr1 = Wrg[(k + 1) * 256 + col];
        float wl2 = Wlg[(k + 2) * 256 + col], wr2 = Wrg[(k + 2) * 256 + col];
        float wl3 = Wlg[(k + 3) * 256 + col], wr3 = Wrg[(k + 3) * 256 + col];
#pragma unroll
        for (int r = 0; r < 16; ++r) {
            float4 hv = *(const float4*)&in[(size_t)(row0 + r) * 64 + k];  // uniform -> s_load_dwordx4
            accL[r] += hv.x * wl0 + hv.y * wl1 + hv.z * wl2 + hv.w * wl3;
            accR[r] += hv.x * wr0 + hv.y * wr1 + hv.z * wr2 + hv.w * wr3;
        }
    }
#pragma unroll
    for (int r = 0; r < 16; ++r) {
        xl[(size_t)(row0 + r) * 256 + col] = accL[r];
        xr[(size_t)(row0 + r) * 256 + col] = accR[r];
    }
}

// ---------------- DPP helpers: 16-lane-group all-reduce sum ----------------
template <int CTRL>
__device__ __forceinline__ float dpp_mov_f32(float x) {
    return __int_as_float(__builtin_amdgcn_update_dpp(0, __float_as_int(x), CTRL, 0xf, 0xf, false));
}
// after this, every lane in each 16-lane group holds the group's sum
__device__ __forceinline__ float group16_reduce_add(float x) {
    x += dpp_mov_f32<0xB1>(x);    // quad_perm [1,0,3,2]  : xor 1
    x += dpp_mov_f32<0x4E>(x);    // quad_perm [2,3,0,1]  : xor 2
    x += dpp_mov_f32<0x124>(x);   // row_ror:4            : + next quad
    x += dpp_mov_f32<0x128>(x);   // row_ror:8            : + other half
    return x;
}

// ---------------- fused GATv2: 1 wave per node, all 4 heads in-wave ----------------
// lane l: head = l>>4, covers row floats [4l, 4l+4)
__global__ __launch_bounds__(256) void gat_node(const float* __restrict__ xl,
                                                const float* __restrict__ xr,
                                                const int* __restrict__ row_ptr,
                                                const int* __restrict__ col_src,
                                                const float* __restrict__ att,     // [4][64] this layer
                                                const float* __restrict__ gbias,   // [64] this layer
                                                const float* __restrict__ h_res,   // residual or null
                                                float* __restrict__ h_out, int n) {
    int wid  = threadIdx.x >> 6;
    int lane = threadIdx.x & 63;
    int node = blockIdx.x * 4 + wid;
    if (node >= n) return;

    const float4* xl4 = (const float4*)xl;   // row = 64 float4
    float4 xrv = ((const float4*)(xr + (size_t)node * NHID))[lane];
    float4 av  = ((const float4*)att)[lane];
    // leaky_relu(z) = 0.6z + 0.4|z| exactly; pre-scale attention vector
    float4 av06 = make_float4(av.x * 0.6f, av.y * 0.6f, av.z * 0.6f, av.w * 0.6f);
    float4 av04 = make_float4(av.x * 0.4f, av.y * 0.4f, av.z * 0.4f, av.w * 0.4f);

    float  m = -INFINITY, s = 0.f;
    float4 acc = make_float4(0.f, 0.f, 0.f, 0.f);

    int e0 = row_ptr[node], e1 = row_ptr[node + 1];
    // edge idx in [e0, e1]; src(idx) = idx<e1 ? col_src[idx] : node (self loop)
    unsigned s0 = (e0 < e1) ? (unsigned)col_src[e0] : (unsigned)node;
    float4 xa = xl4[(size_t)s0 * 64 + lane];
    float4 xb;
    if (e0 + 1 <= e1) {
        unsigned s1 = (e0 + 1 < e1) ? (unsigned)col_src[e0 + 1] : (unsigned)node;
        xb = xl4[(size_t)s1 * 64 + lane];
    } else {
        xb = xa;
    }

    for (int idx = e0; idx <= e1; ++idx) {
        float4 cur = xa;
        xa = xb;
        int pf = idx + 2;
        if (pf <= e1) {
            unsigned sp = (pf < e1) ? (unsigned)col_src[pf] : (unsigned)node;
            xb = xl4[(size_t)sp * 64 + lane];
        }

        float z0 = cur.x + xrv.x;
        float z1 = cur.y + xrv.y;
        float z2 = cur.z + xrv.z;
        float z3 = cur.w + xrv.w;
        float pp;
        pp = fmaf(av06.x, z0, av04.x * fabsf(z0));
        pp = fmaf(av06.y, z1, fmaf(av04.y, fabsf(z1), pp));
        pp = fmaf(av06.z, z2, fmaf(av04.z, fabsf(z2), pp));
        pp = fmaf(av06.w, z3, fmaf(av04.w, fabsf(z3), pp));
        pp = group16_reduce_add(pp);            // per-head score, all lanes of group

        // deferred-max online softmax; branch wave-uniform via __any over heads
        if (__any(pp > m + 8.f)) {
            float mn = fmaxf(m, pp);            // exact online update
            float f  = __expf(m - mn);          // 0 on first edge (m=-inf)
            float w  = __expf(pp - mn);
            acc.x = acc.x * f + w * cur.x;
            acc.y = acc.y * f + w * cur.y;
            acc.z = acc.z * f + w * cur.z;
            acc.w = acc.w * f + w * cur.w;
            s = s * f + w;
            m = mn;
        } else {
            float w = __expf(pp - m);           // bounded by e^8
            acc.x += w * cur.x;
            acc.y += w * cur.y;
            acc.z += w * cur.z;
            acc.w += w * cur.w;
            s += w;
        }
    }

    // per-head weighted mean
    float inv = 1.0f / s;
    float4 v = make_float4(acc.x * inv, acc.y * inv, acc.z * inv, acc.w * inv);
    // cross-head sum: lanes l, l^16, l^32, l^48 hold same channels of heads 0..3
    v.x += __shfl_xor(v.x, 16, 64); v.y += __shfl_xor(v.y, 16, 64);
    v.z += __shfl_xor(v.z, 16, 64); v.w += __shfl_xor(v.w, 16, 64);
    v.x += __shfl_xor(v.x, 32, 64); v.y += __shfl_xor(v.y, 32, 64);
    v.z += __shfl_xor(v.z, 32, 64); v.w += __shfl_xor(v.w, 32, 64);

    if (lane < 16) {
        float4 g = ((const float4*)gbias)[lane];
        float4 o;
        o.x = v.x * 0.25f + g.x;
        o.y = v.y * 0.25f + g.y;
        o.z = v.z * 0.25f + g.z;
        o.w = v.w * 0.25f + g.w;
        o.x = (o.x > 0.f) ? o.x : expm1f(o.x);
        o.y = (o.y > 0.f) ? o.y : expm1f(o.y);
        o.z = (o.z > 0.f) ? o.z : expm1f(o.z);
        o.w = (o.w > 0.f) ? o.w : expm1f(o.w);
        if (h_res) {
            float4 r = ((const float4*)(h_res + (size_t)node * 64))[lane];
            o.x += r.x; o.y += r.y; o.z += r.z; o.w += r.w;
        }
        ((float4*)(h_out + (size_t)node * 64))[lane] = o;
    }
}

// ---------------- column mean of h over all nodes ----------------
__global__ __launch_bounds__(256) void col_sum(const float* __restrict__ h,
                                               float* __restrict__ gsum, int n) {
    int col = threadIdx.x & 63;
    int sub = threadIdx.x >> 6;   // 0..3
    float s = 0.f;
    for (int r = blockIdx.x * 4 + sub; r < n; r += gridDim.x * 4)
        s += h[(size_t)r * 64 + col];
    __shared__ float tmp[4][64];
    tmp[sub][col] = s;
    __syncthreads();
    if (threadIdx.x < 64) {
        int t = threadIdx.x;
        atomicAdd(&gsum[t], tmp[0][t] + tmp[1][t] + tmp[2][t] + tmp[3][t]);
    }
}

// ---------------- output heads, parallel: blocks 0-8 move, 9 price, 10 value ----------
__global__ __launch_bounds__(128) void heads_kernel(const float* __restrict__ h,
                                                    const float* __restrict__ gsum,
                                                    const int* __restrict__ cur_pos,
                                                    const int* __restrict__ valid,
                                                    const int* __restrict__ owned,
                                                    const float* __restrict__ Wm1, const float* __restrict__ bm1,
                                                    const float* __restrict__ Wm2, const float* __restrict__ bm2,
                                                    const float* __restrict__ Wp,  const float* __restrict__ bp,
                                                    const float* __restrict__ Wv1, const float* __restrict__ bv1,
                                                    const float* __restrict__ Wv2, const float* __restrict__ bv2,
                                                    float* __restrict__ out, int n) {
    int blk = blockIdx.x;
    int tid = threadIdx.x;
    int pos = cur_pos[0];

    if (blk < 9) {
        // move logit for candidate blk: hid[tid] over 128 threads, then reduce
        int cand = (blk == 0) ? pos : valid[blk - 1];
        const float* hcur  = h + (size_t)pos  * 64;
        const float* hcand = h + (size_t)cand * 64;
        float a = bm1[tid];
#pragma unroll
        for (int k = 0; k < 64; ++k) a += hcur[k]  * Wm1[k * 128 + tid];
#pragma unroll
        for (int k = 0; k < 64; ++k) a += hcand[k] * Wm1[(64 + k) * 128 + tid];
        a = fmaxf(a, 0.f) * Wm2[tid];
#pragma unroll
        for (int o = 1; o < 64; o <<= 1) a += __shfl_xor(a, o, 64);
        __shared__ float red[2];
        if ((tid & 63) == 0) red[tid >> 6] = a;
        __syncthreads();
        if (tid == 0) out[blk] = red[0] + red[1] + bm2[0];
    } else if (blk == 9) {
        // price logits: 10 nodes x 3
        if (tid < 30) {
            int i = tid / 3, cc = tid % 3;
            int node = owned[i];
            const float* hn = h + (size_t)node * 64;
            float a = bp[cc];
#pragma unroll
            for (int k = 0; k < 64; ++k) a += hn[k] * Wp[k * 3 + cc];
            out[9 + tid] = a;
        }
    } else {
        // value head: g = [gsum/n, h[pos]]
        float invn = 1.0f / (float)n;
        const float* hcur = h + (size_t)pos * 64;
        float a = 0.f;
        if (tid < 64) {
            a = bv1[tid];
#pragma unroll
            for (int k = 0; k < 64; ++k) a += (gsum[k] * invn) * Wv1[k * 64 + tid];
#pragma unroll
            for (int k = 0; k < 64; ++k) a += hcur[k] * Wv1[(64 + k) * 64 + tid];
            a = fmaxf(a, 0.f) * Wv2[tid];
#pragma unroll
            for (int o = 1; o < 64; o <<= 1) a += __shfl_xor(a, o, 64);
            if (tid == 0) out[39] = a + bv2[0];
        }
    }
}

extern "C" void kernel_launch(void* const* d_in, const int* in_sizes, int n_in,
                              void* d_out, int out_size, void* d_ws, size_t ws_size,
                              hipStream_t stream) {
    const float* nf    = (const float*)d_in[0];
    const int*   ei    = (const int*)d_in[1];
    const int*   cpos  = (const int*)d_in[2];
    const int*   valid = (const int*)d_in[3];
    const int*   owned = (const int*)d_in[4];
    const float* Wl    = (const float*)d_in[5];
    const float* bl    = (const float*)d_in[6];
    const float* Wr    = (const float*)d_in[7];
    const float* br    = (const float*)d_in[8];
    const float* att   = (const float*)d_in[9];
    const float* gbias = (const float*)d_in[10];
    const float* Wm1 = (const float*)d_in[11];
    const float* bm1 = (const float*)d_in[12];
    const float* Wm2 = (const float*)d_in[13];
    const float* bm2 = (const float*)d_in[14];
    const float* Wp  = (const float*)d_in[15];
    const float* bp  = (const float*)d_in[16];
    const float* Wv1 = (const float*)d_in[17];
    const float* bv1 = (const float*)d_in[18];
    const float* Wv2 = (const float*)d_in[19];
    const float* bv2 = (const float*)d_in[20];
    float* out = (float*)d_out;

    int n = in_sizes[0] / 64;      // 50000
    int E = in_sizes[1] / 2;       // 800000
    const int* srcp = ei;
    const int* dstp = ei + E;

    // workspace carve
    char* w = (char*)d_ws;
    auto alloc = [&](size_t bytes) -> char* {
        char* p = w;
        w += (bytes + 255) & ~(size_t)255;
        return p;
    };
    float* xl       = (float*)alloc((size_t)n * NHID * 4);
    float* xr       = (float*)alloc((size_t)n * NHID * 4);
    float* hA       = (float*)alloc((size_t)n * 64 * 4);
    float* hB       = (float*)alloc((size_t)n * 64 * 4);
    float* gsum     = (float*)alloc(64 * 4);
    int*   row_ptr  = (int*)alloc((size_t)(n + 1) * 4);
    int*   row_fill = (int*)alloc((size_t)n * 4);
    int*   col_src  = (int*)alloc((size_t)E * 4);
    int*   partials = (int*)alloc(256 * 4);

    int nblk = (n + 255) / 256;    // 196

    // ---- CSR by dst ----
    hipMemsetAsync(row_fill, 0, (size_t)n * 4, stream);
    count_deg<<<(E + 255) / 256, 256, 0, stream>>>(dstp, row_fill, E);
    scan_partial<<<nblk, 256, 0, stream>>>(row_fill, row_ptr, partials, n);
    scan_partials_scan<<<1, 256, 0, stream>>>(partials, row_ptr, nblk, n);
    scan_add_offsets<<<nblk, 256, 0, stream>>>(row_ptr, partials, n);
    copy_i32<<<(n + 255) / 256, 256, 0, stream>>>(row_ptr, row_fill, n);
    scatter_edges<<<(E + 255) / 256, 256, 0, stream>>>(srcp, dstp, row_fill, col_src, E);

    // ---- 5 GATv2 layers ----
    const float* hin = nf;
    float* hnext = hB;
    for (int i = 0; i < LAYERS; ++i) {
        const float* Wli = Wl + (size_t)i * 64 * 256;
        const float* Wri = Wr + (size_t)i * 64 * 256;
        gemm2_64x256<<<(n + 15) / 16, 256, 0, stream>>>(hin, Wli, bl + i * 256,
                                                        Wri, br + i * 256, xl, xr, n);
        const float* res = (i == 0) ? nullptr : hin;
        float* outp = (i == 0) ? hA : hnext;
        gat_node<<<(n + 3) / 4, 256, 0, stream>>>(xl, xr, row_ptr, col_src,
                                                  att + i * HEADS * 64, gbias + i * 64,
                                                  res, outp, n);
        if (i == 0) {
            hin = hA; hnext = hB;
        } else {
            const float* t = hin;
            hin = outp;
            hnext = (float*)t;
        }
    }

    // ---- heads ----
    hipMemsetAsync(gsum, 0, 64 * 4, stream);
    col_sum<<<256, 256, 0, stream>>>(hin, gsum, n);
    heads_kernel<<<11, 128, 0, stream>>>(hin, gsum, cpos, valid, owned,
                                         Wm1, bm1, Wm2, bm2, Wp, bp,
                                         Wv1, bv1, Wv2, bv2, out, n);
}